// Round 4
// baseline (241.834 us; speedup 1.0000x reference)
//
#include <hip/hip_runtime.h>
#include <stdint.h>
#include <stddef.h>

#define M_DIM 2048
#define N_DIM 4096
#define K_DIM 4352
#define H_DIM 1024
#define X_DIM 2304

// workspace layout (bytes)
#define A_OFF 0u
#define B_OFF 17825792u                 // 2048*4352*2

typedef __bf16 bf16x8 __attribute__((ext_vector_type(8)));
typedef float f32x4 __attribute__((ext_vector_type(4)));

__device__ __forceinline__ unsigned short f32_to_bf16(float f) {
    unsigned u = __float_as_uint(f);
    u += 0x7FFFu + ((u >> 16) & 1u);     // round-to-nearest-even
    return (unsigned short)(u >> 16);
}

__device__ __forceinline__ float sigm_(float x) { return 1.f / (1.f + __expf(-x)); }
__device__ __forceinline__ float tanh_(float x) {
    x = fminf(15.f, fmaxf(-15.f, x));
    float e = __expf(2.f * x);
    return (e - 1.f) / (e + 1.f);
}

// ---------------------------------------------------------------------------
// Kernel 1 (unchanged): pack z -> A, W_all gate-interleaved -> B. bf16.
// ---------------------------------------------------------------------------
__global__ __launch_bounds__(256) void convert_kernel(
    const float* __restrict__ x, const float* __restrict__ pt,
    const float* __restrict__ pl,
    const float* __restrict__ Wi, const float* __restrict__ Wf,
    const float* __restrict__ Wo, const float* __restrict__ Ws,
    unsigned short* __restrict__ Abf, unsigned short* __restrict__ Bbf)
{
    const int row = blockIdx.x;                  // 0..6143
    const float* srow = nullptr;
    unsigned short* drow;
    if (row < M_DIM) {
        drow = Abf + (size_t)row * K_DIM;
    } else {
        int n = row - M_DIM;                      // 0..4095
        int g = n >> 10, h = n & 1023;
        const float* W = (g == 0) ? Wi : (g == 1) ? Wf : (g == 2) ? Wo : Ws;
        srow = W + (size_t)h * K_DIM;
        drow = Bbf + (size_t)(h * 4 + g) * K_DIM;
    }

    for (int c8 = threadIdx.x; c8 < K_DIM / 8; c8 += 256) {
        int col = c8 * 8;
        const float* s;
        if (row < M_DIM) {
            if (col < X_DIM)              s = x  + (size_t)row * X_DIM + col;
            else if (col < X_DIM + H_DIM) s = pt + (size_t)row * H_DIM + (col - X_DIM);
            else                          s = pl + (size_t)row * H_DIM + (col - X_DIM - H_DIM);
        } else {
            s = srow + col;
        }
        float4 v0 = ((const float4*)s)[0];
        float4 v1 = ((const float4*)s)[1];
        union { unsigned short h[8]; uint4 u; } r;
        r.h[0] = f32_to_bf16(v0.x); r.h[1] = f32_to_bf16(v0.y);
        r.h[2] = f32_to_bf16(v0.z); r.h[3] = f32_to_bf16(v0.w);
        r.h[4] = f32_to_bf16(v1.x); r.h[5] = f32_to_bf16(v1.y);
        r.h[6] = f32_to_bf16(v1.z); r.h[7] = f32_to_bf16(v1.w);
        *(uint4*)(drow + col) = r.u;
    }
}

// ---------------------------------------------------------------------------
// Kernel 2: fused GEMM + gates. Round-4 change: WAVE TILE 128x64 (was 64x64).
// Block = 4 waves (256 thr) computing a 256x128 tile; grid 8x32 = 256 = 1/CU.
// Per K=32 half-tile per wave: 12 ds_read_b128 (8 A + 4 B) feed 32 MFMAs ->
// FLOP/LDS-byte doubles vs 64x64 (the invariant that pinned r0-r3 at 36%).
// Ring of 4 x 24KB buffers; single barrier per phase; counted vmcnt(6)
// (6 global_load_lds per wave per stage, 2 half-tiles in flight); register
// fragment double-buffer (reads for half p+1 issue before MFMAs of half p,
// 1 wave/SIMD -> in-wave ILP is the overlap mechanism).
// ---------------------------------------------------------------------------
__global__ __launch_bounds__(256, 1) void gemm_fused(
    const unsigned short* __restrict__ A,   // [M_DIM, K_DIM] bf16
    const unsigned short* __restrict__ B,   // [N_DIM, K_DIM] bf16, gate-interleaved
    const float* __restrict__ old_state,    // [2048, 1024]
    const float* __restrict__ bi, const float* __restrict__ bfv,
    const float* __restrict__ bo, const float* __restrict__ bs,
    float* __restrict__ out)                // [2048, 1024]
{
    // ring slot c at c*24576: A half [256 rows][4 slots of 16B] = 16384 B,
    // B half [128 rows][4 slots] = 8192 B at +16384. 4 slots = 96 KB.
    // sP (256*68*4 = 69632 B) aliases the ring in the epilogue.
    __shared__ __align__(16) char smem[98304];
    float* sP = (float*)smem;

    const int tid  = threadIdx.x;
    const int lane = tid & 63;
    const int wave = tid >> 6;              // 0..3
    const int wm = (wave >> 1) * 128;       // 0 | 128
    const int wn = (wave & 1) * 64;         // 0 | 64

    // XCD-aware decode: xcd b&7 owns n-tiles 4*xcd..4*xcd+3 (B panel ~4.5MB)
    const int b   = blockIdx.x;             // 0..255
    const int xcd = b & 7;
    const int j   = b >> 3;                 // 0..31
    const int m0  = (j >> 2) * 256;         // 8 m-tiles
    const int n0  = (xcd * 4 + (j & 3)) * 128;  // 32 n-tiles

    // staging: thread u deposits 16B at slot i*256+u; row = slot>>2 = i*64+(u>>2),
    // kslot = u&3, pre-swizzled source k-block = kslot ^ ((row>>1)&3) = (u&3)^((u>>3)&3)
    const int urow = tid >> 2;              // 0..63
    const int ukb  = (tid & 3) ^ ((tid >> 3) & 3);
    const unsigned short* Asrc = A + (size_t)(m0 + urow) * K_DIM + ukb * 8;
    const unsigned short* Bsrc = B + (size_t)(n0 + urow) * K_DIM + ukb * 8;

    // fragment reads: A row = wm + i*16 + fr (i=0..7), B row = wn + j*16 + fr
    // (j=0..3); k-block kb0 = lane>>4, swizzled slot = kb0 ^ ((fr>>1)&3)
    const int fr  = lane & 15;
    const int kb0 = lane >> 4;
    const int swz = (kb0 ^ ((fr >> 1) & 3)) * 16;
    const int aoff = (wm + fr) * 64 + swz;            // + i*1024
    const int boff = 16384 + (wn + fr) * 64 + swz;    // + j*1024

    f32x4 acc[8][4];
#pragma unroll
    for (int i = 0; i < 8; ++i)
#pragma unroll
        for (int jj = 0; jj < 4; ++jj) acc[i][jj] = (f32x4){0.f, 0.f, 0.f, 0.f};

    // stage half-tile h (k in [h*32, h*32+32)) into ring slot c: 6 loads/thread
    auto stage = [&](int h, int c) {
        const size_t koff = (size_t)h * 32;
#pragma unroll
        for (int i = 0; i < 4; ++i)
            __builtin_amdgcn_global_load_lds(
                (const __attribute__((address_space(1))) unsigned*)(Asrc + (size_t)i * 64 * K_DIM + koff),
                (__attribute__((address_space(3))) unsigned*)(smem + c * 24576 + i * 4096 + wave * 1024),
                16, 0, 0);
#pragma unroll
        for (int i = 0; i < 2; ++i)
            __builtin_amdgcn_global_load_lds(
                (const __attribute__((address_space(1))) unsigned*)(Bsrc + (size_t)i * 64 * K_DIM + koff),
                (__attribute__((address_space(3))) unsigned*)(smem + c * 24576 + 16384 + i * 4096 + wave * 1024),
                16, 0, 0);
    };

    // two fragment register sets (explicit names -- rule #20: static indexing)
    bf16x8 aA[8], bA[4], aB[8], bB[4];

#define VM6  asm volatile("s_waitcnt vmcnt(6)"  ::: "memory")
#define VM0  asm volatile("s_waitcnt vmcnt(0)"  ::: "memory")
#define VMNONE ((void)0)

#define READS(AN, BN, NBUF)                                                     \
    _Pragma("unroll")                                                           \
    for (int i_ = 0; i_ < 8; ++i_)                                              \
        AN[i_] = *(const bf16x8*)(smem + (NBUF) * 24576 + aoff + i_ * 1024);    \
    _Pragma("unroll")                                                           \
    for (int j_ = 0; j_ < 4; ++j_)                                              \
        BN[j_] = *(const bf16x8*)(smem + (NBUF) * 24576 + boff + j_ * 1024);

#define MFMAS(AC, BC)                                                           \
    _Pragma("unroll")                                                           \
    for (int i_ = 0; i_ < 8; ++i_)                                              \
        _Pragma("unroll")                                                       \
        for (int j_ = 0; j_ < 4; ++j_)                                          \
            acc[i_][j_] = __builtin_amdgcn_mfma_f32_16x16x32_bf16(              \
                AC[i_], BC[j_], acc[i_][j_], 0, 0, 0);

    // Phase p: reads(half p+1) into alternate set, stage half p+3, MFMA on
    // current set (its data landed a full phase ago), vmcnt(6) retires half
    // p+2 (read next phase), one barrier.
#define PHASE(AC, BC, AN, BN, NBUF, SH, DOSTAGE, VMLINE, DOBAR)                 \
    do {                                                                        \
        READS(AN, BN, NBUF);                                                    \
        if (DOSTAGE) stage((SH), (SH) & 3);                                     \
        __builtin_amdgcn_sched_barrier(0);                                      \
        MFMAS(AC, BC);                                                          \
        __builtin_amdgcn_sched_barrier(0);                                      \
        VMLINE;                                                                 \
        if (DOBAR) __builtin_amdgcn_s_barrier();                                \
    } while (0)

    // prologue: stage halves 0,1,2 (18 loads); vmcnt(6) -> halves 0,1 landed;
    // barrier; preload frags(0) into set A.
    stage(0, 0); stage(1, 1); stage(2, 2);
    VM6;
    __builtin_amdgcn_s_barrier();
    READS(aA, bA, 0);

    // 136 halves (K = 136*32). Ledger entering phase p: outstanding = half
    // p+2 (6 loads); stage(p+3) -> 12; VM6 retires half p+2.
    for (int p4 = 0; p4 < 132; p4 += 4) {
        PHASE(aA, bA, aB, bB, 1, p4 + 3, true, VM6, true);
        PHASE(aB, bB, aA, bA, 2, p4 + 4, true, VM6, true);
        PHASE(aA, bA, aB, bB, 3, p4 + 5, true, VM6, true);
        PHASE(aB, bB, aA, bA, 0, p4 + 6, true, VM6, true);
    }
    PHASE(aA, bA, aB, bB, 1, 135, true,  VM6,    true);   // p=132: stage 135; retire 134
    PHASE(aB, bB, aA, bA, 2, 0,   false, VM0,    true);   // p=133: retire 135
    PHASE(aA, bA, aB, bB, 3, 0,   false, VMNONE, false);  // p=134: reads(135)
    MFMAS(aB, bB);                                        // p=135

#undef PHASE
#undef READS
#undef MFMAS
#undef VM6
#undef VM0
#undef VMNONE

    // ---- fused epilogue: two n-half passes -------------------------------
    // C/D layout: col = lane&15 (n), row = (lane>>4)*4 + reg (m)
    const int cw = lane & 15;
    const int rw = (lane >> 4) * 4;
    const int hl = tid & 15;                // h within pass
    const int rb = tid >> 4;                // 0..15

    for (int p = 0; p < 2; ++p) {
        __syncthreads();                    // K-loop / pass p-1 readers done
        if ((wave & 1) == p) {              // 2 waves (wm=0,128) own n-half p
#pragma unroll
            for (int i = 0; i < 8; ++i)
#pragma unroll
                for (int jj = 0; jj < 4; ++jj)
#pragma unroll
                    for (int r = 0; r < 4; ++r)
                        sP[(wm + i * 16 + rw + r) * 68 + jj * 16 + cw] = acc[i][jj][r];
        }
        __syncthreads();                    // sP populated

        const int hg = (n0 >> 2) + p * 16 + hl;   // global hidden index
        const float b_i = bi[hg], b_f = bfv[hg], b_o = bo[hg], b_s = bs[hg];
#pragma unroll
        for (int k = 0; k < 16; ++k) {
            const int row = rb + 16 * k;          // 0..255
            float4 g = *(const float4*)(sP + row * 68 + hl * 4);
            const size_t oidx = (size_t)(m0 + row) * H_DIM + hg;
            float old = old_state[oidx];
            float ig = sigm_(g.x + b_i);
            float fg = sigm_(g.y + b_f);
            float og = sigm_(g.z + b_o);
            float ts = tanh_(g.w + b_s);
            out[oidx] = og * tanh_(fg * old + ig * ts);
        }
    }
}

// ---------------------------------------------------------------------------
extern "C" void kernel_launch(void* const* d_in, const int* in_sizes, int n_in,
                              void* d_out, int out_size, void* d_ws, size_t ws_size,
                              hipStream_t stream) {
    const float* x   = (const float*)d_in[0];
    const float* pt  = (const float*)d_in[1];
    const float* pl  = (const float*)d_in[2];
    const float* old = (const float*)d_in[3];
    const float* Wi  = (const float*)d_in[4];
    const float* bi  = (const float*)d_in[5];
    const float* Wf  = (const float*)d_in[6];
    const float* bf  = (const float*)d_in[7];
    const float* Wo  = (const float*)d_in[8];
    const float* bo  = (const float*)d_in[9];
    const float* Ws  = (const float*)d_in[10];
    const float* bs  = (const float*)d_in[11];
    float* out = (float*)d_out;

    char* ws = (char*)d_ws;
    unsigned short* Abf = (unsigned short*)(ws + A_OFF);
    unsigned short* Bbf = (unsigned short*)(ws + B_OFF);

    // 1) pack/convert: one block per destination row
    convert_kernel<<<M_DIM + N_DIM, 256, 0, stream>>>(x, pt, pl, Wi, Wf, Wo, Ws, Abf, Bbf);

    // 2) fused GEMM + gates, XCD-swizzled 1-D grid, 1 block/CU, 4 waves
    gemm_fused<<<256, 256, 0, stream>>>(Abf, Bbf, old, bi, bf, bo, bs, out);
}